// Round 15
// baseline (1368.869 us; speedup 1.0000x reference)
//
#include <hip/hip_runtime.h>
#include <hip/hip_bf16.h>

#define B_GRAPHS 64
#define NPER     2048
#define T_NODES  (B_GRAPHS*NPER)
#define D_DIM    256
#define U_DIM    128
#define TU       384   // 3*U
#define XPW      768   // 2*TU (fwd|bwd)

typedef unsigned short ushortT;
typedef unsigned int   uint32;

typedef __attribute__((ext_vector_type(4))) float  f32x4;
typedef __attribute__((ext_vector_type(8))) __bf16 bf16x8;
typedef _Float16 f16;
typedef __attribute__((ext_vector_type(8))) _Float16 f16x8;

#define GAS __attribute__((address_space(1)))
#define LOG2E_F 1.4426950408889634f

static __device__ __forceinline__ ushortT f2bf(float f) {
  union { float f; uint32 u; } a; a.f = f;
  uint32 u = a.u;
  return (ushortT)((u + 0x7fffu + ((u >> 16) & 1u)) >> 16);   // RTNE
}
static __device__ __forceinline__ float bf2f(ushortT h) {
  union { uint32 u; float f; } a; a.u = ((uint32)h) << 16; return a.f;
}
static __device__ __forceinline__ float rcpf(float x) {
#if __has_builtin(__builtin_amdgcn_rcpf)
  return __builtin_amdgcn_rcpf(x);
#else
  return 1.0f / x;
#endif
}
static __device__ __forceinline__ float exp2f_hw(float x) {
#if __has_builtin(__builtin_amdgcn_exp2f)
  return __builtin_amdgcn_exp2f(x);
#else
  return __expf(0.69314718055994531f * x);
#endif
}
static __device__ __forceinline__ ushortT gload_u16(const ushortT* p) {
  return *(const GAS ushortT*)p;
}
static __device__ __forceinline__ void gstore_u16(ushortT* p, ushortT v) {
  *(GAS ushortT*)p = v;
}

// ---------------- prep: Wt[2][768][256] bf16 (transposed concat of K_fwd|K_bwd), b0[2][768] f32
// z,r columns prescaled by log2e; h columns by 2*log2e (rec uses exp2 directly).
__global__ __launch_bounds__(256) void prep_kernel(
    const float* __restrict__ Kf, const float* __restrict__ Kb,
    const float* __restrict__ bfw, const float* __restrict__ bbw,
    ushortT* __restrict__ Wt, float* __restrict__ b0)
{
  int idx = blockIdx.x * 256 + threadIdx.x;
  if (idx < 2 * XPW * D_DIM) {
    int l = idx / (XPW * D_DIM);
    int rem = idx % (XPW * D_DIM);
    int c = rem / D_DIM, k = rem % D_DIM;
    float v = (c < TU) ? Kf[(size_t)l * D_DIM * TU + (size_t)k * TU + c]
                       : Kb[(size_t)l * D_DIM * TU + (size_t)k * TU + (c - TU)];
    float sc = ((c % TU) < 256) ? LOG2E_F : 2.0f * LOG2E_F;
    Wt[idx] = f2bf(v * sc);
  } else {
    int i2 = idx - 2 * XPW * D_DIM;
    if (i2 < 2 * XPW) {
      int l = i2 / XPW, c = i2 % XPW;
      float v = (c < TU) ? bfw[l * 2 * TU + c] : bbw[l * 2 * TU + (c - TU)];
      float sc = ((c % TU) < 256) ? LOG2E_F : 2.0f * LOG2E_F;
      b0[i2] = v * sc;
    }
  }
}

// ---------------- nodeof[g][slot] = node index ; L[g] = leaf count (positions are a perm of 1..L)
__global__ __launch_bounds__(256) void nodeofL_kernel(
    const int* __restrict__ pos, int* __restrict__ nodeof, int* __restrict__ L)
{
  int g = blockIdx.x, tid = threadIdx.x;
  __shared__ int red[256];
  int cnt = 0;
  for (int i = 0; i < NPER / 256; ++i) {
    int t = g * NPER + i * 256 + tid;
    int p = pos[t];
    if (p) { nodeof[g * NPER + p - 1] = t; cnt++; }
  }
  red[tid] = cnt; __syncthreads();
  for (int s = 128; s > 0; s >>= 1) {
    if (tid < s) red[tid] += red[tid + s];
    __syncthreads();
  }
  if (tid == 0) L[g] = red[0];
}

#if __has_builtin(__builtin_amdgcn_global_load_lds)
#define GLD_LDS(gsrc, ldst) \
  __builtin_amdgcn_global_load_lds((const GAS void*)(gsrc), \
                                   (__attribute__((address_space(3))) void*)(ldst), 16, 0, 0)
#define HAVE_GLD_LDS 1
#else
#define HAVE_GLD_LDS 0
#endif

// ---------------- xp[row][768] = A[row][0..255] @ Wt^T + b0   (bf16 MFMA, 128x128 tiles, BK=32)
// mode 0: A row r gathered from states (f32 -> bf16) via nodeof ; mode 1: A = dense bf16 (y)
__global__ __launch_bounds__(256) void gemm_kernel(
    const float* __restrict__ statesA, const ushortT* __restrict__ Adense,
    const ushortT* __restrict__ Wt, const float* __restrict__ b0,
    const int* __restrict__ nodeof, const int* __restrict__ L,
    ushortT* __restrict__ xp, int layer, int mode)
{
  int mblk = blockIdx.x, nblk = blockIdx.y;
  int g = mblk >> 4;
  int sBase = (mblk & 15) << 7;
  int Lg = L[g];
  if (sBase >= Lg) return;   // whole row-block is padding

  __shared__ __align__(16) ushortT As[128 * 32];
  __shared__ __align__(16) ushortT Bs[128 * 32];

  int tid = threadIdx.x;
  int lane = tid & 63, wid = tid >> 6;
  int wr = wid >> 1, wc = wid & 1;
  f32x4 acc[4][4];
  for (int i = 0; i < 4; i++) for (int n = 0; n < 4; n++) acc[i][n] = (f32x4){0.f,0.f,0.f,0.f};

  for (int kb = 0; kb < 8; ++kb) {
    __syncthreads();
    // stage B: Wt tile [128 cols][32 k] (Wt is pre-transposed: row=col, 512B row stride)
    for (int c = 0; c < 2; ++c) {
      int flat = c * 4096 + tid * 16;
      int col = flat >> 6;
      size_t srcB = ((size_t)(layer * XPW + nblk * 128 + col)) * 512 + kb * 64 + (flat & 63);
#if HAVE_GLD_LDS
      GLD_LDS((const char*)Wt + srcB, (char*)Bs + c * 4096 + wid * 1024);
#else
      *(uint4*)((char*)Bs + flat) = *(const uint4*)((const char*)Wt + srcB);
#endif
    }
    // stage A
    if (mode) {
      for (int c = 0; c < 2; ++c) {
        int flat = c * 4096 + tid * 16;
        int row = flat >> 6;
        size_t srcA = ((size_t)(mblk * 128 + row)) * 512 + kb * 64 + (flat & 63);
#if HAVE_GLD_LDS
        GLD_LDS((const char*)Adense + srcA, (char*)As + c * 4096 + wid * 1024);
#else
        *(uint4*)((char*)As + flat) = *(const uint4*)((const char*)Adense + srcA);
#endif
      }
    } else {
      for (int c = 0; c < 2; ++c) {
        int flat = c * 4096 + tid * 16;
        int row = flat >> 6;
        int s = sBase + row;
        if (s < Lg) {
          int nt = nodeof[g * NPER + s];
          const float* sp = statesA + (size_t)nt * D_DIM + kb * 32 + ((flat & 63) >> 1);
          float4 u0 = *(const float4*)sp;
          float4 u1 = *(const float4*)(sp + 4);
          union { ushortT us[8]; uint4 v; } pk;
          pk.us[0] = f2bf(u0.x); pk.us[1] = f2bf(u0.y); pk.us[2] = f2bf(u0.z); pk.us[3] = f2bf(u0.w);
          pk.us[4] = f2bf(u1.x); pk.us[5] = f2bf(u1.y); pk.us[6] = f2bf(u1.z); pk.us[7] = f2bf(u1.w);
          *(uint4*)((char*)As + flat) = pk.v;
        }
      }
    }
    __syncthreads();

    bf16x8 af[4], bfr[4];
    for (int i = 0; i < 4; i++) {
      int off = (wr * 64 + i * 16 + (lane & 15)) * 32 + (lane >> 4) * 8;
      af[i] = *(const bf16x8*)&As[off];
    }
    for (int n = 0; n < 4; n++) {
      int off = (wc * 64 + n * 16 + (lane & 15)) * 32 + (lane >> 4) * 8;
      bfr[n] = *(const bf16x8*)&Bs[off];
    }
    for (int i = 0; i < 4; i++)
      for (int n = 0; n < 4; n++)
        acc[i][n] = __builtin_amdgcn_mfma_f32_16x16x32_bf16(af[i], bfr[n], acc[i][n], 0, 0, 0);
  }

  // epilogue: + bias, store bf16.  C/D layout: col = lane&15, row = (lane>>4)*4 + v
  for (int n = 0; n < 4; n++) {
    int gcol = nblk * 128 + wc * 64 + n * 16 + (lane & 15);
    float bb = b0[layer * XPW + gcol];
    for (int i = 0; i < 4; i++) {
      int rowBase = mblk * 128 + wr * 64 + i * 16 + (lane >> 4) * 4;
      for (int v = 0; v < 4; v++)
        xp[(size_t)(rowBase + v) * XPW + gcol] = f2bf(acc[i][n][v] + bb);
    }
  }
}

// ---------------- recurrence (single-chain MFMA matvec): 1 WG (4 waves, 256 thr) per (graph, dir).
// Per step: h(1x128) @ R(128x384) via mfma_f32_16x16x32_f16. Wave w owns 32 units
// (j0 = w*32): 6 col-tiles {z:j0, z:j0+16, r:j0, r:j0+16, hg:j0, hg:j0+16} x 4 K-steps
// = 24 MFMA. A-frag trick: every lane loads h[k] at k=(lane>>4)*8+e -> ALL 16 A-rows
// identical -> every lane's D[v] is the valid matvec for col = tilebase + (lane&15)
// (no garbage anywhere). Gates for 2 units/lane computed on all lanes (redundant x4),
// stores guarded to lane<16. Per step per wave: 4 ds_read_b128 + 2 ds_write_b16,
// ZERO bpermutes (MFMA does the K-reduction) — vs r14's 8 reads + 3 bpermutes.
// Fragment layouts copied from the verified gemm kernel. R/b prescaled log2e / 2log2e.
// ONE raw s_barrier per step, lgkmcnt-only drain; depth-4 xp prefetch, rolling pointers.
__global__ __launch_bounds__(256) void rec_kernel(
    const ushortT* __restrict__ xp,
    const float* __restrict__ Rf, const float* __restrict__ Rb,
    const float* __restrict__ bfw, const float* __restrict__ bbw,
    const int* __restrict__ L, ushortT* __restrict__ y, int layer)
{
  int g = blockIdx.x, dir = blockIdx.y;
  int Lg = L[g];
  if (Lg == 0) return;
  int tid = threadIdx.x;
  int wave = tid >> 6, lane = tid & 63;
  int l2 = lane & 15;
  int j0 = wave * 32;
  int u0 = j0 + l2, u1 = j0 + 16 + l2;

  __shared__ __align__(16) f16 hpk[2][128];

  const float* Rsrc = (dir ? Rb : Rf) + (size_t)layer * U_DIM * TU;
  const float* b1p  = (dir ? bbw : bfw) + layer * 2 * TU + TU;

  // B-frags: tile t (gate = t>>1, colbase = j0 + (t&1)*16) x kstep q.
  // B[k][col] with col = colbase + (lane&15), k = q*32 + (lane>>4)*8 + e  (gemm layout)
  f16x8 bw[6][4];
  #pragma unroll
  for (int t = 0; t < 6; ++t) {
    int gate = t >> 1;
    float sc = (gate < 2) ? LOG2E_F : 2.0f * LOG2E_F;
    int col = gate * 128 + j0 + (t & 1) * 16 + l2;
    #pragma unroll
    for (int q = 0; q < 4; ++q) {
      union { f16 h[8]; f16x8 v; } pk;
      #pragma unroll
      for (int e = 0; e < 8; ++e) {
        int k = q * 32 + (lane >> 4) * 8 + e;
        pk.h[e] = (f16)(Rsrc[(size_t)k * TU + col] * sc);
      }
      bw[t][q] = pk.v;
    }
  }
  float bz0 = b1p[u0] * LOG2E_F,                bz1 = b1p[u1] * LOG2E_F;
  float br0 = b1p[128 + u0] * LOG2E_F,          br1 = b1p[128 + u1] * LOG2E_F;
  float bh0 = b1p[256 + u0] * (2.0f * LOG2E_F), bh1 = b1p[256 + u1] * (2.0f * LOG2E_F);

  if (tid < 128) hpk[0][tid] = (f16)0.0f;
  float hreg0 = 0.0f, hreg1 = 0.0f;
  __syncthreads();

  size_t xbase = (size_t)g * NPER * XPW + (size_t)dir * TU;
  int pos0 = dir ? (Lg - 1) : 0;
  const int xstep = dir ? -XPW : XPW;
  const int ystep = dir ? -D_DIM : D_DIM;
  const ushortT* xnext = xp + xbase + (size_t)pos0 * XPW;
  ushortT* ynext = y + ((size_t)(g * NPER + pos0)) * D_DIM + dir * U_DIM;

#define LOADX(S0,S1,S2,S3,S4,S5, COND)                                           \
  if (COND) {                                                                    \
    S0 = gload_u16(xnext + u0);       S1 = gload_u16(xnext + u1);                \
    S2 = gload_u16(xnext + 128 + u0); S3 = gload_u16(xnext + 128 + u1);          \
    S4 = gload_u16(xnext + 256 + u0); S5 = gload_u16(xnext + 256 + u1);          \
  }                                                                              \
  xnext += xstep;

  // depth-4 prologue
  ushortT Xa0=0,Xa1=0,Xa2=0,Xa3=0,Xa4=0,Xa5=0;
  ushortT Xb0=0,Xb1=0,Xb2=0,Xb3=0,Xb4=0,Xb5=0;
  ushortT Xc0=0,Xc1=0,Xc2=0,Xc3=0,Xc4=0,Xc5=0;
  ushortT Xd0=0,Xd1=0,Xd2=0,Xd3=0,Xd4=0,Xd5=0;
  LOADX(Xa0,Xa1,Xa2,Xa3,Xa4,Xa5, true)
  LOADX(Xb0,Xb1,Xb2,Xb3,Xb4,Xb5, 1 < Lg)
  LOADX(Xc0,Xc1,Xc2,Xc3,Xc4,Xc5, 2 < Lg)
  LOADX(Xd0,Xd1,Xd2,Xd3,Xd4,Xd5, 3 < Lg)

#define MFMA_F16 __builtin_amdgcn_mfma_f32_16x16x32_f16

#define GRU_STEP(P, X0,X1,X2,X3,X4,X5, SS)                                       \
  {                                                                              \
    const int s_ = (SS);                                                         \
    /* A-frags: h of prev step; k = (lane>>4)*8+e per kstep (all rows equal) */  \
    const char* hb = (const char*)&hpk[P][0] + ((lane >> 4) * 16);               \
    f16x8 a0 = *(const f16x8*)(hb);                                              \
    f16x8 a1 = *(const f16x8*)(hb + 64);                                         \
    f16x8 a2 = *(const f16x8*)(hb + 128);                                        \
    f16x8 a3 = *(const f16x8*)(hb + 192);                                        \
    float xz0f = bf2f(X0), xz1f = bf2f(X1);                                      \
    float xr0f = bf2f(X2), xr1f = bf2f(X3);                                      \
    float xh0f = bf2f(X4), xh1f = bf2f(X5);                                      \
    LOADX(X0,X1,X2,X3,X4,X5, s_ + 4 < Lg)                                        \
    const f32x4 zv = {0.f, 0.f, 0.f, 0.f};                                       \
    f32x4 t0 = MFMA_F16(a0, bw[0][0], zv, 0, 0, 0);                              \
    f32x4 t1 = MFMA_F16(a0, bw[1][0], zv, 0, 0, 0);                              \
    f32x4 t2 = MFMA_F16(a0, bw[2][0], zv, 0, 0, 0);                              \
    f32x4 t3 = MFMA_F16(a0, bw[3][0], zv, 0, 0, 0);                              \
    f32x4 t4 = MFMA_F16(a0, bw[4][0], zv, 0, 0, 0);                              \
    f32x4 t5 = MFMA_F16(a0, bw[5][0], zv, 0, 0, 0);                              \
    t0 = MFMA_F16(a1, bw[0][1], t0, 0, 0, 0);                                    \
    t1 = MFMA_F16(a1, bw[1][1], t1, 0, 0, 0);                                    \
    t2 = MFMA_F16(a1, bw[2][1], t2, 0, 0, 0);                                    \
    t3 = MFMA_F16(a1, bw[3][1], t3, 0, 0, 0);                                    \
    t4 = MFMA_F16(a1, bw[4][1], t4, 0, 0, 0);                                    \
    t5 = MFMA_F16(a1, bw[5][1], t5, 0, 0, 0);                                    \
    t0 = MFMA_F16(a2, bw[0][2], t0, 0, 0, 0);                                    \
    t1 = MFMA_F16(a2, bw[1][2], t1, 0, 0, 0);                                    \
    t2 = MFMA_F16(a2, bw[2][2], t2, 0, 0, 0);                                    \
    t3 = MFMA_F16(a2, bw[3][2], t3, 0, 0, 0);                                    \
    t4 = MFMA_F16(a2, bw[4][2], t4, 0, 0, 0);                                    \
    t5 = MFMA_F16(a2, bw[5][2], t5, 0, 0, 0);                                    \
    t0 = MFMA_F16(a3, bw[0][3], t0, 0, 0, 0);                                    \
    t1 = MFMA_F16(a3, bw[1][3], t1, 0, 0, 0);                                    \
    t2 = MFMA_F16(a3, bw[2][3], t2, 0, 0, 0);                                    \
    t3 = MFMA_F16(a3, bw[3][3], t3, 0, 0, 0);                                    \
    t4 = MFMA_F16(a3, bw[4][3], t4, 0, 0, 0);                                    \
    t5 = MFMA_F16(a3, bw[5][3], t5, 0, 0, 0);                                    \
    /* every lane's t*[0..3] equal across rows; use element 0 */                 \
    float z0 = rcpf(1.0f + exp2f_hw(-(xz0f + t0[0] + bz0)));                     \
    float z1 = rcpf(1.0f + exp2f_hw(-(xz1f + t1[0] + bz1)));                     \
    float r0 = rcpf(1.0f + exp2f_hw(-(xr0f + t2[0] + br0)));                     \
    float r1 = rcpf(1.0f + exp2f_hw(-(xr1f + t3[0] + br1)));                     \
    float a0v = xh0f + r0 * (t4[0] + bh0);                                       \
    float a1v = xh1f + r1 * (t5[0] + bh1);                                       \
    float e0 = exp2f_hw(__builtin_fabsf(a0v));                                   \
    float e1 = exp2f_hw(__builtin_fabsf(a1v));                                   \
    float th0 = 1.0f - 2.0f * rcpf(e0 + 1.0f);                                   \
    float th1 = 1.0f - 2.0f * rcpf(e1 + 1.0f);                                   \
    float c0 = __builtin_copysignf(th0, a0v);                                    \
    float c1 = __builtin_copysignf(th1, a1v);                                    \
    float hn0 = c0 + z0 * (hreg0 - c0); hreg0 = hn0;                             \
    float hn1 = c1 + z1 * (hreg1 - c1); hreg1 = hn1;                             \
    if (lane < 16) {                                                             \
      gstore_u16(ynext + u0, f2bf(hn0));                                         \
      gstore_u16(ynext + u1, f2bf(hn1));                                         \
      hpk[(P) ^ 1][u0] = (f16)hn0;                                               \
      hpk[(P) ^ 1][u1] = (f16)hn1;                                               \
    }                                                                            \
    ynext += ystep;                                                              \
    asm volatile("s_waitcnt lgkmcnt(0)" ::: "memory");                           \
    __builtin_amdgcn_sched_barrier(0);                                           \
    __builtin_amdgcn_s_barrier();                                                \
    __builtin_amdgcn_sched_barrier(0);                                           \
  }

  for (int s = 0; s < Lg; s += 4) {
    GRU_STEP(0, Xa0,Xa1,Xa2,Xa3,Xa4,Xa5, s);
    if (s + 1 < Lg) GRU_STEP(1, Xb0,Xb1,Xb2,Xb3,Xb4,Xb5, s + 1);
    if (s + 2 < Lg) GRU_STEP(0, Xc0,Xc1,Xc2,Xc3,Xc4,Xc5, s + 2);
    if (s + 3 < Lg) GRU_STEP(1, Xd0,Xd1,Xd2,Xd3,Xd4,Xd5, s + 3);
  }
#undef GRU_STEP
#undef MFMA_F16
#undef LOADX
}

// ---------------- unpack: leaf -> y (bf16->f32), non-leaf -> states copy
__global__ __launch_bounds__(256) void unpack_kernel(
    const float* __restrict__ states, const int* __restrict__ pos,
    const ushortT* __restrict__ y, float* __restrict__ out)
{
  int node = blockIdx.x * 4 + (threadIdx.x >> 6);
  int lane = threadIdx.x & 63;
  int p = pos[node];
  int g = node >> 11;
  float4 v;
  if (p) {
    const ushortT* yp = y + (size_t)(g * NPER + p - 1) * D_DIM + lane * 4;
    v = make_float4(bf2f(yp[0]), bf2f(yp[1]), bf2f(yp[2]), bf2f(yp[3]));
  } else {
    v = *(const float4*)(states + (size_t)node * D_DIM + lane * 4);
  }
  *(float4*)(out + (size_t)node * D_DIM + lane * 4) = v;
}

extern "C" void kernel_launch(void* const* d_in, const int* in_sizes, int n_in,
                              void* d_out, int out_size, void* d_ws, size_t ws_size,
                              hipStream_t stream) {
  const float* states = (const float*)d_in[0];
  const int*   pos    = (const int*)d_in[1];
  // d_in[2] graph_sizes (uniform 2048), d_in[3] training (0) — unused
  const float* Kf  = (const float*)d_in[4];
  const float* Rf  = (const float*)d_in[5];
  const float* bfw = (const float*)d_in[6];
  const float* Kb  = (const float*)d_in[7];
  const float* Rb  = (const float*)d_in[8];
  const float* bbw = (const float*)d_in[9];

  char* ws = (char*)d_ws;
  // layout: L(256B) | nodeof(512KB) | Wt(768KB) | b0(6KB) | xp(201.3MB) | y(67.1MB)  ~= 270MB
  int*     L      = (int*)(ws + 0);
  int*     nodeof = (int*)(ws + 256);
  ushortT* Wt     = (ushortT*)(ws + 524544);
  float*   b0     = (float*)(ws + 1310976);
  ushortT* xp     = (ushortT*)(ws + 1317120);
  ushortT* y      = (ushortT*)(ws + 202643712);

  prep_kernel<<<1542, 256, 0, stream>>>(Kf, Kb, bfw, bbw, Wt, b0);
  nodeofL_kernel<<<64, 256, 0, stream>>>(pos, nodeof, L);

  dim3 ggrid(1024, 6);
  dim3 rgrid(64, 2);   // 1 chain per WG

  // layer 0
  gemm_kernel<<<ggrid, 256, 0, stream>>>(states, (const ushortT*)nullptr, Wt, b0, nodeof, L, xp, 0, 0);
  rec_kernel<<<rgrid, 256, 0, stream>>>(xp, Rf, Rb, bfw, bbw, L, y, 0);
  // layer 1
  gemm_kernel<<<ggrid, 256, 0, stream>>>(states, y, Wt, b0, nodeof, L, xp, 1, 1);
  rec_kernel<<<rgrid, 256, 0, stream>>>(xp, Rf, Rb, bfw, bbw, L, y, 1);

  unpack_kernel<<<32768, 256, 0, stream>>>(states, pos, y, (float*)d_out);
}

// Round 16
// 1336.262 us; speedup vs baseline: 1.0244x; 1.0244x over previous
//
#include <hip/hip_runtime.h>
#include <hip/hip_bf16.h>

#define B_GRAPHS 64
#define NPER     2048
#define T_NODES  (B_GRAPHS*NPER)
#define D_DIM    256
#define U_DIM    128
#define TU       384   // 3*U
#define XPW      768   // 2*TU (fwd|bwd)

typedef unsigned short ushortT;
typedef unsigned int   uint32;

typedef __attribute__((ext_vector_type(4))) float  f32x4;
typedef __attribute__((ext_vector_type(8))) __bf16 bf16x8;
typedef _Float16 f16;
typedef __attribute__((ext_vector_type(2))) _Float16 f16x2;

#define GAS __attribute__((address_space(1)))
#define LOG2E_F 1.4426950408889634f

static __device__ __forceinline__ ushortT f2bf(float f) {
  union { float f; uint32 u; } a; a.f = f;
  uint32 u = a.u;
  return (ushortT)((u + 0x7fffu + ((u >> 16) & 1u)) >> 16);   // RTNE
}
static __device__ __forceinline__ float bf2f(ushortT h) {
  union { uint32 u; float f; } a; a.u = ((uint32)h) << 16; return a.f;
}
static __device__ __forceinline__ f16x2 u2h(uint32 u) {
  union { uint32 u; f16x2 h; } x; x.u = u; return x.h;
}
static __device__ __forceinline__ float dot2f(f16x2 a, f16x2 b, float c) {
#if __has_builtin(__builtin_amdgcn_fdot2)
  return __builtin_amdgcn_fdot2(a, b, c, false);
#else
  return c + (float)a.x * (float)b.x + (float)a.y * (float)b.y;
#endif
}
static __device__ __forceinline__ float rcpf(float x) {
#if __has_builtin(__builtin_amdgcn_rcpf)
  return __builtin_amdgcn_rcpf(x);
#else
  return 1.0f / x;
#endif
}
static __device__ __forceinline__ float exp2f_hw(float x) {
#if __has_builtin(__builtin_amdgcn_exp2f)
  return __builtin_amdgcn_exp2f(x);
#else
  return __expf(0.69314718055994531f * x);
#endif
}
static __device__ __forceinline__ ushortT gload_u16(const ushortT* p) {
  return *(const GAS ushortT*)p;
}
static __device__ __forceinline__ void gstore_u16(ushortT* p, ushortT v) {
  *(GAS ushortT*)p = v;
}
static __device__ __forceinline__ int gload_i32(const int* p) {
  return *(const GAS int*)p;
}
static __device__ __forceinline__ void gstore_f32(float* p, float v) {
  *(GAS float*)p = v;
}

// sum over lane pairs (l, l^32): PROVEN path only (permlane abandoned after r3/r4/r11).
static __device__ __forceinline__ float xor32_sum(float v) {
  return v + __shfl_xor(v, 32);
}

// ---------------- prep: Wt[2][768][256] bf16 (transposed concat of K_fwd|K_bwd), b0[2][768] f32
// z,r columns prescaled by log2e; h columns by 2*log2e (rec uses exp2 directly).
__global__ __launch_bounds__(256) void prep_kernel(
    const float* __restrict__ Kf, const float* __restrict__ Kb,
    const float* __restrict__ bfw, const float* __restrict__ bbw,
    ushortT* __restrict__ Wt, float* __restrict__ b0)
{
  int idx = blockIdx.x * 256 + threadIdx.x;
  if (idx < 2 * XPW * D_DIM) {
    int l = idx / (XPW * D_DIM);
    int rem = idx % (XPW * D_DIM);
    int c = rem / D_DIM, k = rem % D_DIM;
    float v = (c < TU) ? Kf[(size_t)l * D_DIM * TU + (size_t)k * TU + c]
                       : Kb[(size_t)l * D_DIM * TU + (size_t)k * TU + (c - TU)];
    float sc = ((c % TU) < 256) ? LOG2E_F : 2.0f * LOG2E_F;
    Wt[idx] = f2bf(v * sc);
  } else {
    int i2 = idx - 2 * XPW * D_DIM;
    if (i2 < 2 * XPW) {
      int l = i2 / XPW, c = i2 % XPW;
      float v = (c < TU) ? bfw[l * 2 * TU + c] : bbw[l * 2 * TU + (c - TU)];
      float sc = ((c % TU) < 256) ? LOG2E_F : 2.0f * LOG2E_F;
      b0[i2] = v * sc;
    }
  }
}

// ---------------- nodeof[g][slot] = node index ; L[g] = leaf count (positions are a perm of 1..L)
__global__ __launch_bounds__(256) void nodeofL_kernel(
    const int* __restrict__ pos, int* __restrict__ nodeof, int* __restrict__ L)
{
  int g = blockIdx.x, tid = threadIdx.x;
  __shared__ int red[256];
  int cnt = 0;
  for (int i = 0; i < NPER / 256; ++i) {
    int t = g * NPER + i * 256 + tid;
    int p = pos[t];
    if (p) { nodeof[g * NPER + p - 1] = t; cnt++; }
  }
  red[tid] = cnt; __syncthreads();
  for (int s = 128; s > 0; s >>= 1) {
    if (tid < s) red[tid] += red[tid + s];
    __syncthreads();
  }
  if (tid == 0) L[g] = red[0];
}

#if __has_builtin(__builtin_amdgcn_global_load_lds)
#define GLD_LDS(gsrc, ldst) \
  __builtin_amdgcn_global_load_lds((const GAS void*)(gsrc), \
                                   (__attribute__((address_space(3))) void*)(ldst), 16, 0, 0)
#define HAVE_GLD_LDS 1
#else
#define HAVE_GLD_LDS 0
#endif

// ---------------- xp[row][768] = A[row][0..255] @ Wt^T + b0   (bf16 MFMA, 128x128 tiles, BK=32)
// mode 0: A row r gathered from states (f32 -> bf16) via nodeof ; mode 1: A = dense bf16 (y)
__global__ __launch_bounds__(256) void gemm_kernel(
    const float* __restrict__ statesA, const ushortT* __restrict__ Adense,
    const ushortT* __restrict__ Wt, const float* __restrict__ b0,
    const int* __restrict__ nodeof, const int* __restrict__ L,
    ushortT* __restrict__ xp, int layer, int mode)
{
  int mblk = blockIdx.x, nblk = blockIdx.y;
  int g = mblk >> 4;
  int sBase = (mblk & 15) << 7;
  int Lg = L[g];
  if (sBase >= Lg) return;   // whole row-block is padding

  __shared__ __align__(16) ushortT As[128 * 32];
  __shared__ __align__(16) ushortT Bs[128 * 32];

  int tid = threadIdx.x;
  int lane = tid & 63, wid = tid >> 6;
  int wr = wid >> 1, wc = wid & 1;
  f32x4 acc[4][4];
  for (int i = 0; i < 4; i++) for (int n = 0; n < 4; n++) acc[i][n] = (f32x4){0.f,0.f,0.f,0.f};

  for (int kb = 0; kb < 8; ++kb) {
    __syncthreads();
    // stage B: Wt tile [128 cols][32 k] (Wt is pre-transposed: row=col, 512B row stride)
    for (int c = 0; c < 2; ++c) {
      int flat = c * 4096 + tid * 16;
      int col = flat >> 6;
      size_t srcB = ((size_t)(layer * XPW + nblk * 128 + col)) * 512 + kb * 64 + (flat & 63);
#if HAVE_GLD_LDS
      GLD_LDS((const char*)Wt + srcB, (char*)Bs + c * 4096 + wid * 1024);
#else
      *(uint4*)((char*)Bs + flat) = *(const uint4*)((const char*)Wt + srcB);
#endif
    }
    // stage A
    if (mode) {
      for (int c = 0; c < 2; ++c) {
        int flat = c * 4096 + tid * 16;
        int row = flat >> 6;
        size_t srcA = ((size_t)(mblk * 128 + row)) * 512 + kb * 64 + (flat & 63);
#if HAVE_GLD_LDS
        GLD_LDS((const char*)Adense + srcA, (char*)As + c * 4096 + wid * 1024);
#else
        *(uint4*)((char*)As + flat) = *(const uint4*)((const char*)Adense + srcA);
#endif
      }
    } else {
      for (int c = 0; c < 2; ++c) {
        int flat = c * 4096 + tid * 16;
        int row = flat >> 6;
        int s = sBase + row;
        if (s < Lg) {
          int nt = nodeof[g * NPER + s];
          const float* sp = statesA + (size_t)nt * D_DIM + kb * 32 + ((flat & 63) >> 1);
          float4 u0 = *(const float4*)sp;
          float4 u1 = *(const float4*)(sp + 4);
          union { ushortT us[8]; uint4 v; } pk;
          pk.us[0] = f2bf(u0.x); pk.us[1] = f2bf(u0.y); pk.us[2] = f2bf(u0.z); pk.us[3] = f2bf(u0.w);
          pk.us[4] = f2bf(u1.x); pk.us[5] = f2bf(u1.y); pk.us[6] = f2bf(u1.z); pk.us[7] = f2bf(u1.w);
          *(uint4*)((char*)As + flat) = pk.v;
        }
      }
    }
    __syncthreads();

    bf16x8 af[4], bfr[4];
    for (int i = 0; i < 4; i++) {
      int off = (wr * 64 + i * 16 + (lane & 15)) * 32 + (lane >> 4) * 8;
      af[i] = *(const bf16x8*)&As[off];
    }
    for (int n = 0; n < 4; n++) {
      int off = (wc * 64 + n * 16 + (lane & 15)) * 32 + (lane >> 4) * 8;
      bfr[n] = *(const bf16x8*)&Bs[off];
    }
    for (int i = 0; i < 4; i++)
      for (int n = 0; n < 4; n++)
        acc[i][n] = __builtin_amdgcn_mfma_f32_16x16x32_bf16(af[i], bfr[n], acc[i][n], 0, 0, 0);
  }

  // epilogue: + bias, store bf16.  C/D layout: col = lane&15, row = (lane>>4)*4 + v
  for (int n = 0; n < 4; n++) {
    int gcol = nblk * 128 + wc * 64 + n * 16 + (lane & 15);
    float bb = b0[layer * XPW + gcol];
    for (int i = 0; i < 4; i++) {
      int rowBase = mblk * 128 + wr * 64 + i * 16 + (lane >> 4) * 4;
      for (int v = 0; v < 4; v++)
        xp[(size_t)(rowBase + v) * XPW + gcol] = f2bf(acc[i][n][v] + bb);
    }
  }
}

// ---------------- recurrence: 1 WG (4 waves, 256 thr) per (graph, dir) — r14 structure
// (best found: rec 504 us; r13 reorder / r15 MFMA / r6-r9 packing all regressed).
// lane layout: j = wave*32+(lane&31) (GRU unit), half = lane>>5 (K half).
// Each lane: 3 gate cols {j,128+j,256+j}, 32 f16x2 R regs/gate (prescaled log2e / 2log2e).
// K-half combine via __shfl_xor(32). h via ping-pong LDS, ONE raw s_barrier per step,
// lgkmcnt-only drain (xp loads / y,out stores vmcnt-only, stay in flight). Depth-4 xp
// prefetch, rolling pointers. WOUT=1 (layer 1): store f32 DIRECTLY to out[node] via a
// rolling nodeof pointer (loaded at step start; ~900 idle cyc cover its L2 latency) —
// lets unpack skip leaf rows entirely and drops the y bf16 round-trip on the output.
template <int WOUT>
__global__ __launch_bounds__(256) void rec_kernel(
    const ushortT* __restrict__ xp,
    const float* __restrict__ Rf, const float* __restrict__ Rb,
    const float* __restrict__ bfw, const float* __restrict__ bbw,
    const int* __restrict__ L, ushortT* __restrict__ y,
    const int* __restrict__ nodeof, float* __restrict__ outp, int layer)
{
  int g = blockIdx.x, dir = blockIdx.y;
  int Lg = L[g];
  if (Lg == 0) return;
  int tid = threadIdx.x;
  int wave = tid >> 6, lane = tid & 63;
  int jl = lane & 31, half = lane >> 5;
  int j = wave * 32 + jl;                 // 0..127

  __shared__ __align__(16) f16 hpk[2][128];

  const float* R  = (dir ? Rb : Rf) + (size_t)layer * U_DIM * TU;
  const float* b1 = (dir ? bbw : bfw) + layer * 2 * TU + TU;

  // loop-invariant bpermute addr not needed (shfl_xor proven); weights prescaled
  f16x2 rz[32], rg[32], rh[32];
  #pragma unroll
  for (int m = 0; m < 32; ++m) {
    int k = half * 64 + 2 * m;
    const float* p0 = R + (size_t)k * TU;
    const float* p1 = p0 + TU;
    f16x2 a, b, c;
    a.x = (f16)(p0[j] * LOG2E_F);                a.y = (f16)(p1[j] * LOG2E_F);
    b.x = (f16)(p0[128 + j] * LOG2E_F);          b.y = (f16)(p1[128 + j] * LOG2E_F);
    c.x = (f16)(p0[256 + j] * (2.0f * LOG2E_F)); c.y = (f16)(p1[256 + j] * (2.0f * LOG2E_F));
    rz[m] = a; rg[m] = b; rh[m] = c;
  }
  float bz = half ? 0.0f : b1[j] * LOG2E_F;
  float br = half ? 0.0f : b1[128 + j] * LOG2E_F;
  float bh = half ? 0.0f : b1[256 + j] * (2.0f * LOG2E_F);

  if (tid < 128) hpk[0][tid] = (f16)0.0f;
  float hreg = 0.0f;
  __syncthreads();

  size_t xbase = (size_t)g * NPER * XPW + (size_t)dir * TU;
  int pos0 = dir ? (Lg - 1) : 0;
  const int xstep = dir ? -XPW : XPW;
  const int ystep = dir ? -D_DIM : D_DIM;
  const int ndstep = dir ? -1 : 1;
  const ushortT* xnext = xp + xbase + (size_t)pos0 * XPW;     // rolling prefetch ptr
  ushortT* ynext = y + ((size_t)(g * NPER + pos0)) * D_DIM + dir * U_DIM + j;
  const int* ndp = nodeof + g * NPER + pos0;                  // rolling node-index ptr

  // depth-4 prologue (pointer advances unconditionally; loads guarded, so no OOB access)
  ushortT xz0=0,xr0=0,xh0=0, xz1=0,xr1=0,xh1=0, xz2=0,xr2=0,xh2=0, xz3=0,xr3=0,xh3=0;
  { xz0 = gload_u16(xnext+j); xr0 = gload_u16(xnext+128+j); xh0 = gload_u16(xnext+256+j); }
  xnext += xstep;
  if (1 < Lg) { xz1 = gload_u16(xnext+j); xr1 = gload_u16(xnext+128+j); xh1 = gload_u16(xnext+256+j); }
  xnext += xstep;
  if (2 < Lg) { xz2 = gload_u16(xnext+j); xr2 = gload_u16(xnext+128+j); xh2 = gload_u16(xnext+256+j); }
  xnext += xstep;
  if (3 < Lg) { xz3 = gload_u16(xnext+j); xr3 = gload_u16(xnext+128+j); xh3 = gload_u16(xnext+256+j); }
  xnext += xstep;

#define GRU_STEP(P, XZ, XR, XH, SS)                                              \
  {                                                                              \
    const int s_ = (SS);                                                         \
    int nd_ = 0;                                                                 \
    if (WOUT) { nd_ = gload_i32(ndp); ndp += ndstep; }                           \
    float xzf = bf2f(XZ), xrf = bf2f(XR), xhf = bf2f(XH);                        \
    if (s_ + 4 < Lg) {                                                           \
      XZ = gload_u16(xnext + j);                                                 \
      XR = gload_u16(xnext + 128 + j);                                           \
      XH = gload_u16(xnext + 256 + j);                                           \
    }                                                                            \
    xnext += xstep;                                                              \
    const uint4* hv = (const uint4*)&hpk[P][half * 64];                          \
    uint32 hw[32];                                                               \
    _Pragma("unroll")                                                            \
    for (int q8 = 0; q8 < 8; ++q8) {                                             \
      uint4 v_ = hv[q8];                                                         \
      hw[4*q8] = v_.x; hw[4*q8+1] = v_.y; hw[4*q8+2] = v_.z; hw[4*q8+3] = v_.w;  \
    }                                                                            \
    float az0 = bz, ar0 = br, ah0 = bh, az1 = 0.f, ar1 = 0.f, ah1 = 0.f;         \
    _Pragma("unroll")                                                            \
    for (int m = 0; m < 32; m += 2) {                                            \
      az0 = dot2f(u2h(hw[m]),   rz[m],   az0);                                   \
      ar0 = dot2f(u2h(hw[m]),   rg[m],   ar0);                                   \
      ah0 = dot2f(u2h(hw[m]),   rh[m],   ah0);                                   \
      az1 = dot2f(u2h(hw[m+1]), rz[m+1], az1);                                   \
      ar1 = dot2f(u2h(hw[m+1]), rg[m+1], ar1);                                   \
      ah1 = dot2f(u2h(hw[m+1]), rh[m+1], ah1);                                   \
    }                                                                            \
    float hz = xor32_sum(az0 + az1);                                             \
    float hr = xor32_sum(ar0 + ar1);                                             \
    float hh = xor32_sum(ah0 + ah1);                                             \
    float z = rcpf(1.0f + exp2f_hw(-(xzf + hz)));                                \
    float r = rcpf(1.0f + exp2f_hw(-(xrf + hr)));                                \
    float a = xhf + r * hh;                                                      \
    float e = exp2f_hw(__builtin_fabsf(a));                                      \
    float th = 1.0f - 2.0f * rcpf(e + 1.0f);                                     \
    float cand = __builtin_copysignf(th, a);                                     \
    float hnew = cand + z * (hreg - cand);                                       \
    hreg = hnew;                                                                 \
    if (half) {                                                                  \
      if (WOUT) {                                                                \
        gstore_f32(outp + (size_t)nd_ * D_DIM + dir * U_DIM + j, hnew);          \
      } else {                                                                   \
        gstore_u16(ynext, f2bf(hnew));                                           \
      }                                                                          \
    } else {                                                                     \
      hpk[(P) ^ 1][j] = (f16)hnew;                                               \
    }                                                                            \
    ynext += ystep;                                                              \
    asm volatile("s_waitcnt lgkmcnt(0)" ::: "memory");                           \
    __builtin_amdgcn_sched_barrier(0);                                           \
    __builtin_amdgcn_s_barrier();                                                \
    __builtin_amdgcn_sched_barrier(0);                                           \
  }

  for (int s = 0; s < Lg; s += 4) {
    GRU_STEP(0, xz0, xr0, xh0, s);
    if (s + 1 < Lg) GRU_STEP(1, xz1, xr1, xh1, s + 1);
    if (s + 2 < Lg) GRU_STEP(0, xz2, xr2, xh2, s + 2);
    if (s + 3 < Lg) GRU_STEP(1, xz3, xr3, xh3, s + 3);
  }
#undef GRU_STEP
}

// ---------------- unpack (non-leaves only; leaves written f32 by layer-1 rec)
__global__ __launch_bounds__(256) void unpack_kernel(
    const float* __restrict__ states, const int* __restrict__ pos,
    float* __restrict__ out)
{
  int node = blockIdx.x * 4 + (threadIdx.x >> 6);
  int lane = threadIdx.x & 63;
  int p = pos[node];
  if (p) return;   // leaf: already written by rec_kernel<1>
  float4 v = *(const float4*)(states + (size_t)node * D_DIM + lane * 4);
  *(float4*)(out + (size_t)node * D_DIM + lane * 4) = v;
}

extern "C" void kernel_launch(void* const* d_in, const int* in_sizes, int n_in,
                              void* d_out, int out_size, void* d_ws, size_t ws_size,
                              hipStream_t stream) {
  const float* states = (const float*)d_in[0];
  const int*   pos    = (const int*)d_in[1];
  // d_in[2] graph_sizes (uniform 2048), d_in[3] training (0) — unused
  const float* Kf  = (const float*)d_in[4];
  const float* Rf  = (const float*)d_in[5];
  const float* bfw = (const float*)d_in[6];
  const float* Kb  = (const float*)d_in[7];
  const float* Rb  = (const float*)d_in[8];
  const float* bbw = (const float*)d_in[9];

  char* ws = (char*)d_ws;
  // layout: L(256B) | nodeof(512KB) | Wt(768KB) | b0(6KB) | xp(201.3MB) | y(67.1MB)  ~= 270MB
  int*     L      = (int*)(ws + 0);
  int*     nodeof = (int*)(ws + 256);
  ushortT* Wt     = (ushortT*)(ws + 524544);
  float*   b0     = (float*)(ws + 1310976);
  ushortT* xp     = (ushortT*)(ws + 1317120);
  ushortT* y      = (ushortT*)(ws + 202643712);

  prep_kernel<<<1542, 256, 0, stream>>>(Kf, Kb, bfw, bbw, Wt, b0);
  nodeofL_kernel<<<64, 256, 0, stream>>>(pos, nodeof, L);

  dim3 ggrid(1024, 6);
  dim3 rgrid(64, 2);

  // layer 0: rec writes y (bf16) for layer-1 gemm
  gemm_kernel<<<ggrid, 256, 0, stream>>>(states, (const ushortT*)nullptr, Wt, b0, nodeof, L, xp, 0, 0);
  rec_kernel<0><<<rgrid, 256, 0, stream>>>(xp, Rf, Rb, bfw, bbw, L, y, nodeof, (float*)d_out, 0);
  // layer 1: rec writes f32 directly to out rows of leaf nodes
  gemm_kernel<<<ggrid, 256, 0, stream>>>(states, y, Wt, b0, nodeof, L, xp, 1, 1);
  rec_kernel<1><<<rgrid, 256, 0, stream>>>(xp, Rf, Rb, bfw, bbw, L, y, nodeof, (float*)d_out, 1);

  unpack_kernel<<<32768, 256, 0, stream>>>(states, pos, (float*)d_out);
}

// Round 17
// 1230.112 us; speedup vs baseline: 1.1128x; 1.0863x over previous
//
#include <hip/hip_runtime.h>
#include <hip/hip_bf16.h>

#define B_GRAPHS 64
#define NPER     2048
#define T_NODES  (B_GRAPHS*NPER)
#define D_DIM    256
#define U_DIM    128
#define TU       384   // 3*U
#define XPW      768   // 2*TU (fwd|bwd)
#define NCB      128   // copy blocks per dir folded into rec layer-0 dispatch

typedef unsigned short ushortT;
typedef unsigned int   uint32;

typedef __attribute__((ext_vector_type(4))) float  f32x4;
typedef __attribute__((ext_vector_type(8))) __bf16 bf16x8;
typedef _Float16 f16;
typedef __attribute__((ext_vector_type(2))) _Float16 f16x2;

#define GAS __attribute__((address_space(1)))
#define LOG2E_F 1.4426950408889634f

static __device__ __forceinline__ ushortT f2bf(float f) {
  union { float f; uint32 u; } a; a.f = f;
  uint32 u = a.u;
  return (ushortT)((u + 0x7fffu + ((u >> 16) & 1u)) >> 16);   // RTNE
}
static __device__ __forceinline__ float bf2f(ushortT h) {
  union { uint32 u; float f; } a; a.u = ((uint32)h) << 16; return a.f;
}
static __device__ __forceinline__ f16x2 u2h(uint32 u) {
  union { uint32 u; f16x2 h; } x; x.u = u; return x.h;
}
static __device__ __forceinline__ float dot2f(f16x2 a, f16x2 b, float c) {
#if __has_builtin(__builtin_amdgcn_fdot2)
  return __builtin_amdgcn_fdot2(a, b, c, false);
#else
  return c + (float)a.x * (float)b.x + (float)a.y * (float)b.y;
#endif
}
static __device__ __forceinline__ float rcpf(float x) {
#if __has_builtin(__builtin_amdgcn_rcpf)
  return __builtin_amdgcn_rcpf(x);
#else
  return 1.0f / x;
#endif
}
static __device__ __forceinline__ float exp2f_hw(float x) {
#if __has_builtin(__builtin_amdgcn_exp2f)
  return __builtin_amdgcn_exp2f(x);
#else
  return __expf(0.69314718055994531f * x);
#endif
}
static __device__ __forceinline__ ushortT gload_u16(const ushortT* p) {
  return *(const GAS ushortT*)p;
}
static __device__ __forceinline__ void gstore_u16(ushortT* p, ushortT v) {
  *(GAS ushortT*)p = v;
}

// sum over lane pairs (l, l^32): PROVEN path only (permlane abandoned after r3/r4/r11).
static __device__ __forceinline__ float xor32_sum(float v) {
  return v + __shfl_xor(v, 32);
}

// ---------------- prep: Wt[2][768][256] bf16 (transposed concat of K_fwd|K_bwd), b0[2][768] f32
// z,r columns prescaled by log2e; h columns by 2*log2e (rec uses exp2 directly).
__global__ __launch_bounds__(256) void prep_kernel(
    const float* __restrict__ Kf, const float* __restrict__ Kb,
    const float* __restrict__ bfw, const float* __restrict__ bbw,
    ushortT* __restrict__ Wt, float* __restrict__ b0)
{
  int idx = blockIdx.x * 256 + threadIdx.x;
  if (idx < 2 * XPW * D_DIM) {
    int l = idx / (XPW * D_DIM);
    int rem = idx % (XPW * D_DIM);
    int c = rem / D_DIM, k = rem % D_DIM;
    float v = (c < TU) ? Kf[(size_t)l * D_DIM * TU + (size_t)k * TU + c]
                       : Kb[(size_t)l * D_DIM * TU + (size_t)k * TU + (c - TU)];
    float sc = ((c % TU) < 256) ? LOG2E_F : 2.0f * LOG2E_F;
    Wt[idx] = f2bf(v * sc);
  } else {
    int i2 = idx - 2 * XPW * D_DIM;
    if (i2 < 2 * XPW) {
      int l = i2 / XPW, c = i2 % XPW;
      float v = (c < TU) ? bfw[l * 2 * TU + c] : bbw[l * 2 * TU + (c - TU)];
      float sc = ((c % TU) < 256) ? LOG2E_F : 2.0f * LOG2E_F;
      b0[i2] = v * sc;
    }
  }
}

// ---------------- nodeof[g][slot] = node index ; L[g] = leaf count (positions are a perm of 1..L)
__global__ __launch_bounds__(256) void nodeofL_kernel(
    const int* __restrict__ pos, int* __restrict__ nodeof, int* __restrict__ L)
{
  int g = blockIdx.x, tid = threadIdx.x;
  __shared__ int red[256];
  int cnt = 0;
  for (int i = 0; i < NPER / 256; ++i) {
    int t = g * NPER + i * 256 + tid;
    int p = pos[t];
    if (p) { nodeof[g * NPER + p - 1] = t; cnt++; }
  }
  red[tid] = cnt; __syncthreads();
  for (int s = 128; s > 0; s >>= 1) {
    if (tid < s) red[tid] += red[tid + s];
    __syncthreads();
  }
  if (tid == 0) L[g] = red[0];
}

#if __has_builtin(__builtin_amdgcn_global_load_lds)
#define GLD_LDS(gsrc, ldst) \
  __builtin_amdgcn_global_load_lds((const GAS void*)(gsrc), \
                                   (__attribute__((address_space(3))) void*)(ldst), 16, 0, 0)
#define HAVE_GLD_LDS 1
#else
#define HAVE_GLD_LDS 0
#endif

// ---------------- xp[row][768] = A[row][0..255] @ Wt^T + b0   (bf16 MFMA, 128x128 tiles, BK=32)
// mode 0: A row r gathered from states (f32 -> bf16) via nodeof ; mode 1: A = dense bf16 (y)
__global__ __launch_bounds__(256) void gemm_kernel(
    const float* __restrict__ statesA, const ushortT* __restrict__ Adense,
    const ushortT* __restrict__ Wt, const float* __restrict__ b0,
    const int* __restrict__ nodeof, const int* __restrict__ L,
    ushortT* __restrict__ xp, int layer, int mode)
{
  int mblk = blockIdx.x, nblk = blockIdx.y;
  int g = mblk >> 4;
  int sBase = (mblk & 15) << 7;
  int Lg = L[g];
  if (sBase >= Lg) return;   // whole row-block is padding

  __shared__ __align__(16) ushortT As[128 * 32];
  __shared__ __align__(16) ushortT Bs[128 * 32];

  int tid = threadIdx.x;
  int lane = tid & 63, wid = tid >> 6;
  int wr = wid >> 1, wc = wid & 1;
  f32x4 acc[4][4];
  for (int i = 0; i < 4; i++) for (int n = 0; n < 4; n++) acc[i][n] = (f32x4){0.f,0.f,0.f,0.f};

  for (int kb = 0; kb < 8; ++kb) {
    __syncthreads();
    // stage B: Wt tile [128 cols][32 k] (Wt is pre-transposed: row=col, 512B row stride)
    for (int c = 0; c < 2; ++c) {
      int flat = c * 4096 + tid * 16;
      int col = flat >> 6;
      size_t srcB = ((size_t)(layer * XPW + nblk * 128 + col)) * 512 + kb * 64 + (flat & 63);
#if HAVE_GLD_LDS
      GLD_LDS((const char*)Wt + srcB, (char*)Bs + c * 4096 + wid * 1024);
#else
      *(uint4*)((char*)Bs + flat) = *(const uint4*)((const char*)Wt + srcB);
#endif
    }
    // stage A
    if (mode) {
      for (int c = 0; c < 2; ++c) {
        int flat = c * 4096 + tid * 16;
        int row = flat >> 6;
        size_t srcA = ((size_t)(mblk * 128 + row)) * 512 + kb * 64 + (flat & 63);
#if HAVE_GLD_LDS
        GLD_LDS((const char*)Adense + srcA, (char*)As + c * 4096 + wid * 1024);
#else
        *(uint4*)((char*)As + flat) = *(const uint4*)((const char*)Adense + srcA);
#endif
      }
    } else {
      for (int c = 0; c < 2; ++c) {
        int flat = c * 4096 + tid * 16;
        int row = flat >> 6;
        int s = sBase + row;
        if (s < Lg) {
          int nt = nodeof[g * NPER + s];
          const float* sp = statesA + (size_t)nt * D_DIM + kb * 32 + ((flat & 63) >> 1);
          float4 u0 = *(const float4*)sp;
          float4 u1 = *(const float4*)(sp + 4);
          union { ushortT us[8]; uint4 v; } pk;
          pk.us[0] = f2bf(u0.x); pk.us[1] = f2bf(u0.y); pk.us[2] = f2bf(u0.z); pk.us[3] = f2bf(u0.w);
          pk.us[4] = f2bf(u1.x); pk.us[5] = f2bf(u1.y); pk.us[6] = f2bf(u1.z); pk.us[7] = f2bf(u1.w);
          *(uint4*)((char*)As + flat) = pk.v;
        }
      }
    }
    __syncthreads();

    bf16x8 af[4], bfr[4];
    for (int i = 0; i < 4; i++) {
      int off = (wr * 64 + i * 16 + (lane & 15)) * 32 + (lane >> 4) * 8;
      af[i] = *(const bf16x8*)&As[off];
    }
    for (int n = 0; n < 4; n++) {
      int off = (wc * 64 + n * 16 + (lane & 15)) * 32 + (lane >> 4) * 8;
      bfr[n] = *(const bf16x8*)&Bs[off];
    }
    for (int i = 0; i < 4; i++)
      for (int n = 0; n < 4; n++)
        acc[i][n] = __builtin_amdgcn_mfma_f32_16x16x32_bf16(af[i], bfr[n], acc[i][n], 0, 0, 0);
  }

  // epilogue: + bias, store bf16.  C/D layout: col = lane&15, row = (lane>>4)*4 + v
  for (int n = 0; n < 4; n++) {
    int gcol = nblk * 128 + wc * 64 + n * 16 + (lane & 15);
    float bb = b0[layer * XPW + gcol];
    for (int i = 0; i < 4; i++) {
      int rowBase = mblk * 128 + wr * 64 + i * 16 + (lane >> 4) * 4;
      for (int v = 0; v < 4; v++)
        xp[(size_t)(rowBase + v) * XPW + gcol] = f2bf(acc[i][n][v] + bb);
    }
  }
}

// ---------------- recurrence: r12 structure EXACTLY (best found: rec 504 us/layer).
// 1 WG (4 waves, 256 thr) per (graph, dir); j = wave*32+(lane&31), half = lane>>5.
// 3 gate cols/lane, 32 f16x2 R regs/gate (prescaled log2e / 2log2e), __shfl_xor(32)
// K-half combine, ping-pong LDS h, ONE raw s_barrier/step with lgkmcnt-only drain,
// depth-4 xp prefetch with rolling pointers.
// COPY==1 (layer 0 dispatch only): blocks with blockIdx.x >= B_GRAPHS take a pure-copy
// branch (states -> out for non-leaf rows) that runs on CUs idle during the latency-bound
// rec window — hides the ~268MB copy for free. Serial step body untouched (r16 lesson:
// never add anything to the step).
template <int COPY>
__global__ __launch_bounds__(256) void rec_kernel(
    const ushortT* __restrict__ xp,
    const float* __restrict__ Rf, const float* __restrict__ Rb,
    const float* __restrict__ bfw, const float* __restrict__ bbw,
    const int* __restrict__ L, ushortT* __restrict__ y, int layer,
    const float* __restrict__ states, const int* __restrict__ pos,
    float* __restrict__ outp)
{
  if (COPY && blockIdx.x >= B_GRAPHS) {
    // ---- hidden copy branch: non-leaf rows of out = states
    int cb = (blockIdx.x - B_GRAPHS) + (blockIdx.y ? NCB : 0);   // 0..2*NCB-1
    int lane = threadIdx.x & 63;
    for (int node = cb * 4 + (threadIdx.x >> 6); node < T_NODES; node += 2 * NCB * 4) {
      if (pos[node] == 0) {
        float4 v = *(const float4*)(states + (size_t)node * D_DIM + lane * 4);
        *(float4*)(outp + (size_t)node * D_DIM + lane * 4) = v;
      }
    }
    return;
  }

  int g = blockIdx.x, dir = blockIdx.y;
  int Lg = L[g];
  if (Lg == 0) return;
  int tid = threadIdx.x;
  int wave = tid >> 6, lane = tid & 63;
  int jl = lane & 31, half = lane >> 5;
  int j = wave * 32 + jl;                 // 0..127

  __shared__ __align__(16) f16 hpk[2][128];

  const float* R  = (dir ? Rb : Rf) + (size_t)layer * U_DIM * TU;
  const float* b1 = (dir ? bbw : bfw) + layer * 2 * TU + TU;

  // recurrent weights into registers (f16x2 over k-pairs, prescaled)
  f16x2 rz[32], rg[32], rh[32];
  #pragma unroll
  for (int m = 0; m < 32; ++m) {
    int k = half * 64 + 2 * m;
    const float* p0 = R + (size_t)k * TU;
    const float* p1 = p0 + TU;
    f16x2 a, b, c;
    a.x = (f16)(p0[j] * LOG2E_F);                a.y = (f16)(p1[j] * LOG2E_F);
    b.x = (f16)(p0[128 + j] * LOG2E_F);          b.y = (f16)(p1[128 + j] * LOG2E_F);
    c.x = (f16)(p0[256 + j] * (2.0f * LOG2E_F)); c.y = (f16)(p1[256 + j] * (2.0f * LOG2E_F));
    rz[m] = a; rg[m] = b; rh[m] = c;
  }
  float bz = half ? 0.0f : b1[j] * LOG2E_F;
  float br = half ? 0.0f : b1[128 + j] * LOG2E_F;
  float bh = half ? 0.0f : b1[256 + j] * (2.0f * LOG2E_F);

  if (tid < 128) hpk[0][tid] = (f16)0.0f;
  float hreg = 0.0f;
  __syncthreads();

  size_t xbase = (size_t)g * NPER * XPW + (size_t)dir * TU;
  int pos0 = dir ? (Lg - 1) : 0;
  const int xstep = dir ? -XPW : XPW;
  const int ystep = dir ? -D_DIM : D_DIM;
  const ushortT* xnext = xp + xbase + (size_t)pos0 * XPW;     // rolling prefetch ptr
  ushortT* ynext = y + ((size_t)(g * NPER + pos0)) * D_DIM + dir * U_DIM + j;

  // depth-4 prologue (pointer advances unconditionally; loads guarded, so no OOB access)
  ushortT xz0=0,xr0=0,xh0=0, xz1=0,xr1=0,xh1=0, xz2=0,xr2=0,xh2=0, xz3=0,xr3=0,xh3=0;
  { xz0 = gload_u16(xnext+j); xr0 = gload_u16(xnext+128+j); xh0 = gload_u16(xnext+256+j); }
  xnext += xstep;
  if (1 < Lg) { xz1 = gload_u16(xnext+j); xr1 = gload_u16(xnext+128+j); xh1 = gload_u16(xnext+256+j); }
  xnext += xstep;
  if (2 < Lg) { xz2 = gload_u16(xnext+j); xr2 = gload_u16(xnext+128+j); xh2 = gload_u16(xnext+256+j); }
  xnext += xstep;
  if (3 < Lg) { xz3 = gload_u16(xnext+j); xr3 = gload_u16(xnext+128+j); xh3 = gload_u16(xnext+256+j); }
  xnext += xstep;

#define GRU_STEP(P, XZ, XR, XH, SS)                                              \
  {                                                                              \
    const int s_ = (SS);                                                         \
    float xzf = bf2f(XZ), xrf = bf2f(XR), xhf = bf2f(XH);                        \
    if (s_ + 4 < Lg) {                                                           \
      XZ = gload_u16(xnext + j);                                                 \
      XR = gload_u16(xnext + 128 + j);                                           \
      XH = gload_u16(xnext + 256 + j);                                           \
    }                                                                            \
    xnext += xstep;                                                              \
    const uint4* hv = (const uint4*)&hpk[P][half * 64];                          \
    uint32 hw[32];                                                               \
    _Pragma("unroll")                                                            \
    for (int q8 = 0; q8 < 8; ++q8) {                                             \
      uint4 v_ = hv[q8];                                                         \
      hw[4*q8] = v_.x; hw[4*q8+1] = v_.y; hw[4*q8+2] = v_.z; hw[4*q8+3] = v_.w;  \
    }                                                                            \
    float az0 = bz, ar0 = br, ah0 = bh, az1 = 0.f, ar1 = 0.f, ah1 = 0.f;         \
    _Pragma("unroll")                                                            \
    for (int m = 0; m < 32; m += 2) {                                            \
      az0 = dot2f(u2h(hw[m]),   rz[m],   az0);                                   \
      ar0 = dot2f(u2h(hw[m]),   rg[m],   ar0);                                   \
      ah0 = dot2f(u2h(hw[m]),   rh[m],   ah0);                                   \
      az1 = dot2f(u2h(hw[m+1]), rz[m+1], az1);                                   \
      ar1 = dot2f(u2h(hw[m+1]), rg[m+1], ar1);                                   \
      ah1 = dot2f(u2h(hw[m+1]), rh[m+1], ah1);                                   \
    }                                                                            \
    float hz = xor32_sum(az0 + az1);                                             \
    float hr = xor32_sum(ar0 + ar1);                                             \
    float hh = xor32_sum(ah0 + ah1);                                             \
    float z = rcpf(1.0f + exp2f_hw(-(xzf + hz)));                                \
    float r = rcpf(1.0f + exp2f_hw(-(xrf + hr)));                                \
    float a = xhf + r * hh;                                                      \
    float e = exp2f_hw(__builtin_fabsf(a));                                      \
    float th = 1.0f - 2.0f * rcpf(e + 1.0f);                                     \
    float cand = __builtin_copysignf(th, a);                                     \
    float hnew = cand + z * (hreg - cand);                                       \
    hreg = hnew;                                                                 \
    if (half) {                                                                  \
      gstore_u16(ynext, f2bf(hnew));                                             \
    } else {                                                                     \
      hpk[(P) ^ 1][j] = (f16)hnew;                                               \
    }                                                                            \
    ynext += ystep;                                                              \
    asm volatile("s_waitcnt lgkmcnt(0)" ::: "memory");                           \
    __builtin_amdgcn_sched_barrier(0);                                           \
    __builtin_amdgcn_s_barrier();                                                \
    __builtin_amdgcn_sched_barrier(0);                                           \
  }

  for (int s = 0; s < Lg; s += 4) {
    GRU_STEP(0, xz0, xr0, xh0, s);
    if (s + 1 < Lg) GRU_STEP(1, xz1, xr1, xh1, s + 1);
    if (s + 2 < Lg) GRU_STEP(0, xz2, xr2, xh2, s + 2);
    if (s + 3 < Lg) GRU_STEP(1, xz3, xr3, xh3, s + 3);
  }
#undef GRU_STEP
}

// ---------------- unpack (leaf rows only; non-leaf rows were copied during rec layer-0)
__global__ __launch_bounds__(256) void unpack_kernel(
    const int* __restrict__ pos, const ushortT* __restrict__ y,
    float* __restrict__ out)
{
  int node = blockIdx.x * 4 + (threadIdx.x >> 6);
  int lane = threadIdx.x & 63;
  int p = pos[node];
  if (!p) return;   // non-leaf: already copied by rec_kernel<1> copy branch
  int g = node >> 11;
  const ushortT* yp = y + (size_t)(g * NPER + p - 1) * D_DIM + lane * 4;
  float4 v = make_float4(bf2f(yp[0]), bf2f(yp[1]), bf2f(yp[2]), bf2f(yp[3]));
  *(float4*)(out + (size_t)node * D_DIM + lane * 4) = v;
}

extern "C" void kernel_launch(void* const* d_in, const int* in_sizes, int n_in,
                              void* d_out, int out_size, void* d_ws, size_t ws_size,
                              hipStream_t stream) {
  const float* states = (const float*)d_in[0];
  const int*   pos    = (const int*)d_in[1];
  // d_in[2] graph_sizes (uniform 2048), d_in[3] training (0) — unused
  const float* Kf  = (const float*)d_in[4];
  const float* Rf  = (const float*)d_in[5];
  const float* bfw = (const float*)d_in[6];
  const float* Kb  = (const float*)d_in[7];
  const float* Rb  = (const float*)d_in[8];
  const float* bbw = (const float*)d_in[9];

  char* ws = (char*)d_ws;
  // layout: L(256B) | nodeof(512KB) | Wt(768KB) | b0(6KB) | xp(201.3MB) | y(67.1MB)  ~= 270MB
  int*     L      = (int*)(ws + 0);
  int*     nodeof = (int*)(ws + 256);
  ushortT* Wt     = (ushortT*)(ws + 524544);
  float*   b0     = (float*)(ws + 1310976);
  ushortT* xp     = (ushortT*)(ws + 1317120);
  ushortT* y      = (ushortT*)(ws + 202643712);

  prep_kernel<<<1542, 256, 0, stream>>>(Kf, Kb, bfw, bbw, Wt, b0);
  nodeofL_kernel<<<64, 256, 0, stream>>>(pos, nodeof, L);

  dim3 ggrid(1024, 6);
  dim3 rgrid0(B_GRAPHS + NCB, 2);   // 128 rec WGs + 256 hidden-copy WGs
  dim3 rgrid1(B_GRAPHS, 2);

  // layer 0 (rec + hidden non-leaf copy on idle CUs)
  gemm_kernel<<<ggrid, 256, 0, stream>>>(states, (const ushortT*)nullptr, Wt, b0, nodeof, L, xp, 0, 0);
  rec_kernel<1><<<rgrid0, 256, 0, stream>>>(xp, Rf, Rb, bfw, bbw, L, y, 0, states, pos, (float*)d_out);
  // layer 1
  gemm_kernel<<<ggrid, 256, 0, stream>>>(states, y, Wt, b0, nodeof, L, xp, 1, 1);
  rec_kernel<0><<<rgrid1, 256, 0, stream>>>(xp, Rf, Rb, bfw, bbw, L, y, 1, states, pos, (float*)d_out);

  unpack_kernel<<<32768, 256, 0, stream>>>(pos, y, (float*)d_out);
}